// Round 14
// baseline (121.603 us; speedup 1.0000x reference)
//
#include <hip/hip_runtime.h>
#include <hip/hip_bf16.h>
#include <stdint.h>

typedef unsigned short ushort_t;

#define BB 4
#define SS 4096
#define DD 2048
#define KKC 64      // K channels
#define HH 32
#define NT (BB*SS)  // 16384 tokens
#define NQKV 192
#define QB 32       // tokens per k_qkv block

// dynamic LDS: 2 bufs x (B 24576 + x 8192) = 65536 B
#define BUF2 32768
#define XOFF 24576

typedef float f32x4 __attribute__((ext_vector_type(4)));
typedef short s16x8 __attribute__((ext_vector_type(8)));

__device__ __forceinline__ ushort_t f2bf(float f) {
    union { float f; uint32_t u; } c; c.f = f;
    uint32_t u = c.u + 0x7fffu + ((c.u >> 16) & 1u);
    return (ushort_t)(u >> 16);
}
__device__ __forceinline__ float bf2f(ushort_t b) {
    union { uint32_t u; float f; } c; c.u = (uint32_t)b << 16; return c.f;
}

__device__ __forceinline__ uint32_t cvtpk(float lo, float hi) {
    uint32_t r;
    asm("v_cvt_pk_bf16_f32 %0, %1, %2" : "=v"(r) : "v"(lo), "v"(hi));
    return r;
}

// D = A(16x32) * B(32x16) + D, bf16 inputs, f32 acc.
// A lane map: row = l&15, k = 8*(l>>4)+e. B: col = l&15, k = 8*(l>>4)+e.
// C/D: col = l&15, row = 4*(l>>4)+reg.
__device__ __forceinline__ void mfma16(f32x4& d, s16x8 a, s16x8 b) {
    asm volatile("v_mfma_f32_16x16x32_bf16 %0, %1, %2, %0" : "+v"(d) : "v"(a), "v"(b));
}

// async global->LDS, 16B per lane; lds dest wave-uniform base (HW adds lane*16).
__device__ __forceinline__ void gload_lds16(const void* gsrc, void* ldst) {
    __builtin_amdgcn_global_load_lds(
        (const __attribute__((address_space(1))) unsigned int*)gsrc,
        (__attribute__((address_space(3))) unsigned int*)ldst,
        16, 0, 0);
}

// -------- merged weight pre-convert + per-col sums --------------------------
// blocks 0..255:  W1' entry E: lane=E&63, f=(E>>6)%12, g=(E>>6)/12
//   col=f*16+(lane&15); k0=g*32+8*(lane>>4); holds qkv_w[col][k]*norm_w[k]
//   (E>=49152 -> W2: n=F*16+(lane&15); k0=kk*32+8*(lane>>4))
// blocks 256..303: S[col]=sum_k bf16(qkv_w*nw); qb2[col]=sum nb*qkv_w + qkv_b
__global__ __launch_bounds__(256) void k_pre(
    const float* __restrict__ qkv_w, const float* __restrict__ nw,
    const float* __restrict__ nb, const float* __restrict__ qkv_b,
    const float* __restrict__ out_w,
    ushort_t* __restrict__ W1, ushort_t* __restrict__ W2,
    float* __restrict__ S, float* __restrict__ qb2) {
    int bid = blockIdx.x;
    if (bid < 256) {
        int E = bid * 256 + threadIdx.x;
        if (E < 49152) {
            int lane = E & 63; int rest = E >> 6;
            int f = rest % 12, g = rest / 12;
            int col = f * 16 + (lane & 15);
            int k0 = g * 32 + 8 * (lane >> 4);
            const float* src = qkv_w + (size_t)col * DD + k0;
            const float* wp = nw + k0;
            union { ushort_t u[8]; uint4 v; } cv;
            #pragma unroll
            for (int e = 0; e < 8; ++e) cv.u[e] = f2bf(src[e] * wp[e]);
            *(uint4*)(W1 + (size_t)E * 8) = cv.v;
        } else {
            int E2 = E - 49152;   // 16384 entries
            int lane = E2 & 63; int rest = E2 >> 6;
            int kk = rest & 1, F = rest >> 1;
            int n = F * 16 + (lane & 15);
            int k0 = kk * 32 + 8 * (lane >> 4);
            const float* src = out_w + (size_t)n * KKC + k0;
            union { ushort_t u[8]; uint4 v; } cv;
            #pragma unroll
            for (int e = 0; e < 8; ++e) cv.u[e] = f2bf(src[e]);
            *(uint4*)(W2 + (size_t)E2 * 8) = cv.v;
        }
    } else {
        int col = (bid - 256) * 4 + (threadIdx.x >> 6);   // 48 blocks -> 192 cols
        int lane = threadIdx.x & 63;
        float s = 0.f, qb = 0.f;
        for (int j = 0; j < 32; ++j) {
            int k = j * 64 + lane;
            float w = qkv_w[(size_t)col * DD + k];
            s += bf2f(f2bf(w * nw[k]));
            qb += nb[k] * w;
        }
        #pragma unroll
        for (int off = 32; off >= 1; off >>= 1) {
            s += __shfl_xor(s, off);
            qb += __shfl_xor(qb, off);
        }
        if (lane == 0) { S[col] = s; qb2[col] = qb + qkv_b[col]; }
    }
}

// ------- fused (LN-folded) QKV GEMM + stats + feature map + kv partials -----
// 32 tokens/block, grid 512 -> 2 blocks/CU (16 waves/CU). 512 thr = 8 waves:
// rg = wave&1 (16 rows), ch = wave>>1 (48 cols = 3 frags).
// BK=64, 32 steps. DOUBLE-buffered staging, counted s_waitcnt vmcnt(4) +
// raw s_barrier (stage(t+1) issued before the wait). T5: s_setprio(1)
// around the MFMA cluster (phase-split schedule, 2 blocks/CU role diversity).
__global__ __launch_bounds__(512, 4) void k_qkv(
    const float* __restrict__ x, const ushort_t* __restrict__ W1,
    const float* __restrict__ S, const float* __restrict__ qb2,
    const float* __restrict__ fm_w, const float* __restrict__ fm_b,
    float* __restrict__ qfeat,          // [NT][64]
    float* __restrict__ kvpart)         // [512 blocks][192]
{
    extern __shared__ __align__(16) char dynlds[];   // 65536 B
    __shared__ float kvred[32][16][6];   // 12288 B
    __shared__ float stats4[4][QB][2];   // 1024 B
    __shared__ float stats[QB][2];       // 256 B

    const int tid = threadIdx.x;
    const int wave = tid >> 6, lane = tid & 63;
    const int rg = wave & 1, ch = wave >> 1;
    const int m0 = blockIdx.x * QB;

    const int rloc = rg * 16 + (lane & 15);
    const int q4 = lane >> 4;
    const int swz = rloc & 7;
    const int fbase = ch * 3;

    // x staging: 512 16B-entries/step, 1 per thread
    const int row0 = tid >> 4;
    const int slot0 = (tid & 15) ^ (row0 & 7);      // pre-swizzled source
    const size_t xg0 = (size_t)(m0 + row0) * DD + slot0 * 4;
    const int xd0 = wave * 1024;                    // wave-uniform byte base

    f32x4 acc[3];
    #pragma unroll
    for (int j = 0; j < 3; ++j) acc[j] = (f32x4){0.f, 0.f, 0.f, 0.f};
    float st1 = 0.f, st2 = 0.f;

#define STAGE(T, OB) do { \
        char* bB_ = dynlds + (OB); \
        char* bX_ = dynlds + (OB) + XOFF; \
        _Pragma("unroll") \
        for (int i_ = 0; i_ < 3; ++i_) { \
            int eb_ = i_ * 512 + wave * 64; \
            gload_lds16((const char*)W1 + ((size_t)(T) * 1536 + eb_ + lane) * 16, \
                        bB_ + eb_ * 16); \
        } \
        gload_lds16(x + xg0 + (size_t)(T) * 64, bX_ + xd0); \
    } while (0)

#define STEP_BODY(OC, T) do { \
        const s16x8* bb_ = (const s16x8*)(dynlds + (OC)); \
        const float* xb_ = (const float*)(dynlds + (OC) + XOFF) + rloc * 64; \
        const bool doStats_ = (((T) & 3) == ch); \
        s16x8 afr0_, afr1_; \
        { \
            int sg0_ = 2 * q4, sg1_ = 8 + 2 * q4; \
            float4 a0_ = *(const float4*)(xb_ + ((sg0_    ) ^ swz) * 4); \
            float4 a1_ = *(const float4*)(xb_ + ((sg0_ + 1) ^ swz) * 4); \
            float4 b0_ = *(const float4*)(xb_ + ((sg1_    ) ^ swz) * 4); \
            float4 b1_ = *(const float4*)(xb_ + ((sg1_ + 1) ^ swz) * 4); \
            if (doStats_) { \
                st1 += a0_.x+a0_.y+a0_.z+a0_.w + a1_.x+a1_.y+a1_.z+a1_.w \
                     + b0_.x+b0_.y+b0_.z+b0_.w + b1_.x+b1_.y+b1_.z+b1_.w; \
                st2 += a0_.x*a0_.x+a0_.y*a0_.y+a0_.z*a0_.z+a0_.w*a0_.w \
                     + a1_.x*a1_.x+a1_.y*a1_.y+a1_.z*a1_.z+a1_.w*a1_.w \
                     + b0_.x*b0_.x+b0_.y*b0_.y+b0_.z*b0_.z+b0_.w*b0_.w \
                     + b1_.x*b1_.x+b1_.y*b1_.y+b1_.z*b1_.z+b1_.w*b1_.w; \
            } \
            union { uint32_t w[4]; s16x8 v; } c0_, c1_; \
            c0_.w[0] = cvtpk(a0_.x, a0_.y); c0_.w[1] = cvtpk(a0_.z, a0_.w); \
            c0_.w[2] = cvtpk(a1_.x, a1_.y); c0_.w[3] = cvtpk(a1_.z, a1_.w); \
            c1_.w[0] = cvtpk(b0_.x, b0_.y); c1_.w[1] = cvtpk(b0_.z, b0_.w); \
            c1_.w[2] = cvtpk(b1_.x, b1_.y); c1_.w[3] = cvtpk(b1_.z, b1_.w); \
            afr0_ = c0_.v; afr1_ = c1_.v; \
        } \
        __builtin_amdgcn_s_setprio(1); \
        _Pragma("unroll") \
        for (int j_ = 0; j_ < 3; ++j_) { \
            s16x8 w0_ = bb_[(fbase + j_) * 64 + lane]; \
            s16x8 w1_ = bb_[(12 + fbase + j_) * 64 + lane]; \
            mfma16(acc[j_], afr0_, w0_); \
            mfma16(acc[j_], afr1_, w1_); \
        } \
        __builtin_amdgcn_s_setprio(0); \
    } while (0)

    STAGE(0, 0);
    for (int t = 0; t < 31; ++t) {
        STAGE(t + 1, ((t + 1) & 1) * BUF2);           // into other buffer
        asm volatile("s_waitcnt vmcnt(4)" ::: "memory");  // stage(t) landed
        __builtin_amdgcn_s_barrier();                 // buf(t) ready block-wide
        __builtin_amdgcn_sched_barrier(0);
        STEP_BODY((t & 1) * BUF2, t);
        __builtin_amdgcn_s_barrier();                 // buf(t) reads done
    }
    asm volatile("s_waitcnt vmcnt(0)" ::: "memory");
    __builtin_amdgcn_s_barrier();
    __builtin_amdgcn_sched_barrier(0);
    STEP_BODY((31 & 1) * BUF2, 31);

    // ---- stats: reduce q4 groups, publish per-ch partials
    st1 += __shfl_xor(st1, 16); st2 += __shfl_xor(st2, 16);
    st1 += __shfl_xor(st1, 32); st2 += __shfl_xor(st2, 32);
    if (lane < 16) { stats4[ch][rloc][0] = st1; stats4[ch][rloc][1] = st2; }
    __syncthreads();    // all LDS reads consumed; stats4 visible

    // ---- C -> LDS overlay (clobbers staging bufs; safe now) + final stats
    float (*cep)[NQKV] = (float (*)[NQKV])dynlds;     // 32x192 f32 = 24 KB
    #pragma unroll
    for (int j = 0; j < 3; ++j) {
        int col = (fbase + j) * 16 + (lane & 15);
        int rbase = rg * 16 + (lane >> 4) * 4;
        #pragma unroll
        for (int r = 0; r < 4; ++r)
            cep[rbase + r][col] = acc[j][r];
    }
    if (tid < QB) {
        float s1 = stats4[0][tid][0] + stats4[1][tid][0] + stats4[2][tid][0] + stats4[3][tid][0];
        float s2 = stats4[0][tid][1] + stats4[1][tid][1] + stats4[2][tid][1] + stats4[3][tid][1];
        float mu = s1 * (1.f / DD);
        float var = s2 * (1.f / DD) - mu * mu;
        stats[tid][0] = mu;
        stats[tid][1] = rsqrtf(var + 1e-5f);
    }
    __syncthreads();

    // ---- per (token, head): LN-affine + feature map + qfeat + kv partials
    const int h = tid & 31, gg = tid >> 5;     // gg 0..15, 2 tokens each
    const float fm00 = fm_w[0], fm01 = fm_w[1], fm10 = fm_w[2], fm11 = fm_w[3];
    const float fb0 = fm_b[0], fb1 = fm_b[1];
    const float Sq0 = S[2*h],      Sq1 = S[2*h+1],      cq0 = qb2[2*h],      cq1 = qb2[2*h+1];
    const float Sk0 = S[64+2*h],   Sk1 = S[64+2*h+1],   ck0 = qb2[64+2*h],   ck1 = qb2[64+2*h+1];
    const float Sv0 = S[128+2*h],  Sv1 = S[128+2*h+1],  cv0 = qb2[128+2*h],  cv1 = qb2[128+2*h+1];
    float kv00=0, kv01=0, kv10=0, kv11=0, ks0=0, ks1=0;
    #pragma unroll
    for (int i = 0; i < 2; ++i) {
        int tt = gg * 2 + i;
        float mu = stats[tt][0], rs = stats[tt][1];
        float f = mu * rs;
        float q0 = rs * cep[tt][2*h]      - f * Sq0 + cq0;
        float q1 = rs * cep[tt][2*h+1]    - f * Sq1 + cq1;
        float k0 = rs * cep[tt][64+2*h]   - f * Sk0 + ck0;
        float k1 = rs * cep[tt][64+2*h+1] - f * Sk1 + ck1;
        float v0 = rs * cep[tt][128+2*h]  - f * Sv0 + cv0;
        float v1 = rs * cep[tt][128+2*h+1]- f * Sv1 + cv1;
        float qp0 = fmaxf(fm00*q0 + fm01*q1 + fb0, 0.f);
        float qp1 = fmaxf(fm10*q0 + fm11*q1 + fb1, 0.f);
        float kp0 = fmaxf(fm00*k0 + fm01*k1 + fb0, 0.f);
        float kp1 = fmaxf(fm10*k0 + fm11*k1 + fb1, 0.f);
        *(float2*)(qfeat + (size_t)(m0 + tt) * KKC + 2*h) = make_float2(qp0, qp1);
        kv00 += kp0*v0; kv01 += kp0*v1; kv10 += kp1*v0; kv11 += kp1*v1;
        ks0 += kp0; ks1 += kp1;
    }
    kvred[h][gg][0]=kv00; kvred[h][gg][1]=kv01; kvred[h][gg][2]=kv10;
    kvred[h][gg][3]=kv11; kvred[h][gg][4]=ks0;  kvred[h][gg][5]=ks1;
    __syncthreads();
    if (tid < 192) {
        int h2 = tid / 6, j = tid % 6;
        float s = 0.f;
        #pragma unroll
        for (int g2 = 0; g2 < 16; ++g2) s += kvred[h2][g2][j];
        kvpart[(size_t)blockIdx.x * 192 + tid] = s;
    }
#undef STAGE
#undef STEP_BODY
}

// ---------------- reduce kv partials (deterministic) ----------------
__global__ void k_red(const float* __restrict__ kvpart, float* __restrict__ kvstate) {
    int idx = blockIdx.x * 256 + threadIdx.x;   // 768 = B*H*6
    if (idx >= BB * HH * 6) return;
    int b = idx / 192, r = idx % 192;
    float s = 0.f;
    for (int blk = 0; blk < 128; ++blk)
        s += kvpart[(size_t)(b * 128 + blk) * 192 + r];
    kvstate[idx] = s;  // [b][h][6]
}

// ---------------- out-projection GEMM (attn inline) + residual -------------
#define CEP_STRIDE 260
__global__ __launch_bounds__(512, 4) void k_out(
    const float* __restrict__ qfeat, const float* __restrict__ kvstate,
    const ushort_t* __restrict__ W2, const float* __restrict__ out_b,
    const float* __restrict__ x, float* __restrict__ out) {
    __shared__ float skv[192];
    __shared__ __align__(16) float cep[32 * CEP_STRIDE];   // 33280 B
    const int tid = threadIdx.x, wave = tid >> 6, lane = tid & 63;
    const int rg = wave & 1, cq = wave >> 1;
    const int mb = blockIdx.x >> 1, nb = blockIdx.x & 1;
    const int m0 = mb * 32;
    const int n0 = nb * 1024;
    const int b = m0 >> 12;
    if (tid < 192) skv[tid] = kvstate[b * 192 + tid];

    const int arow = m0 + rg * 16 + (lane & 15);
    const int ksub = 8 * (lane >> 4);
    float4 qa0 = *(const float4*)(qfeat + (size_t)arow * KKC + ksub);
    float4 qa1 = *(const float4*)(qfeat + (size_t)arow * KKC + ksub + 4);
    float4 qb0 = *(const float4*)(qfeat + (size_t)arow * KKC + 32 + ksub);
    float4 qb1 = *(const float4*)(qfeat + (size_t)arow * KKC + 32 + ksub + 4);
    __syncthreads();

    union { ushort_t u[8]; s16x8 v; } ca, cb;
    {
        float qs[8] = {qa0.x,qa0.y,qa0.z,qa0.w,qa1.x,qa1.y,qa1.z,qa1.w};
        float rs[8] = {qb0.x,qb0.y,qb0.z,qb0.w,qb1.x,qb1.y,qb1.z,qb1.w};
        #pragma unroll
        for (int e = 0; e < 8; e += 2) {
            int h = (ksub + e) >> 1;
            const float* kv = skv + h * 6;
            float q0 = qs[e], q1 = qs[e+1];
            float inv = 1.f / (q0 * kv[4] + q1 * kv[5] + 1e-8f);
            ca.u[e]   = f2bf((q0 * kv[0] + q1 * kv[2]) * inv);
            ca.u[e+1] = f2bf((q0 * kv[1] + q1 * kv[3]) * inv);
            const float* kw = skv + (h + 16) * 6;
            float p0 = rs[e], p1 = rs[e+1];
            float iw = 1.f / (p0 * kw[4] + p1 * kw[5] + 1e-8f);
            cb.u[e]   = f2bf((p0 * kw[0] + p1 * kw[2]) * iw);
            cb.u[e+1] = f2bf((p0 * kw[1] + p1 * kw[3]) * iw);
        }
    }

    f32x4 acc[16];
    #pragma unroll
    for (int j = 0; j < 16; ++j) acc[j] = (f32x4){0.f, 0.f, 0.f, 0.f};
    #pragma unroll
    for (int j = 0; j < 16; ++j) {
        int Fg = (n0 >> 4) + cq + 4 * j;
        s16x8 b0 = *(const s16x8*)(W2 + ((size_t)(Fg * 2 + 0) * 64 + lane) * 8);
        s16x8 b1 = *(const s16x8*)(W2 + ((size_t)(Fg * 2 + 1) * 64 + lane) * 8);
        mfma16(acc[j], ca.v, b0);
        mfma16(acc[j], cb.v, b1);
    }

    const int wrow = rg * 16 + 4 * (lane >> 4);
    #pragma unroll
    for (int n = 0; n < 4; ++n) {
        #pragma unroll
        for (int i = 0; i < 4; ++i) {
            int col = cq * 16 + i * 64 + (lane & 15);
            #pragma unroll
            for (int r = 0; r < 4; ++r)
                cep[(wrow + r) * CEP_STRIDE + col] = acc[4 * n + i][r];
        }
        __syncthreads();
        #pragma unroll
        for (int p = 0; p < 4; ++p) {
            int row = p * 8 + (tid >> 6);
            int c4 = tid & 63;
            float4 c = *(const float4*)(cep + row * CEP_STRIDE + c4 * 4);
            int gcol = n0 + n * 256 + c4 * 4;
            size_t off = (size_t)(m0 + row) * DD + gcol;
            float4 xr = *(const float4*)(x + off);
            float4 ob = *(const float4*)(out_b + gcol);
            float4 o;
            o.x = c.x + ob.x + xr.x; o.y = c.y + ob.y + xr.y;
            o.z = c.z + ob.z + xr.z; o.w = c.w + ob.w + xr.w;
            *(float4*)(out + off) = o;
        }
        __syncthreads();
    }
}

extern "C" void kernel_launch(void* const* d_in, const int* in_sizes, int n_in,
                              void* d_out, int out_size, void* d_ws, size_t ws_size,
                              hipStream_t stream) {
    const float* x     = (const float*)d_in[0];
    const float* nw    = (const float*)d_in[1];
    const float* nb    = (const float*)d_in[2];
    const float* qkv_w = (const float*)d_in[3];
    const float* qkv_b = (const float*)d_in[4];
    const float* fm_w  = (const float*)d_in[5];
    const float* fm_b  = (const float*)d_in[6];
    const float* out_w = (const float*)d_in[7];
    const float* out_b = (const float*)d_in[8];
    float* out = (float*)d_out;

    char* ws = (char*)d_ws;
    ushort_t* W1 = (ushort_t*)ws;     ws += (size_t)NQKV * DD * 2;        // 786432 B
    ushort_t* W2 = (ushort_t*)ws;     ws += (size_t)DD * KKC * 2;         // 262144 B
    float* qfeat = (float*)ws;        ws += (size_t)NT * KKC * 4;         // 4 MiB
    float* kvpart = (float*)ws;       ws += (size_t)512 * 192 * 4;        // 393216 B
    float* kvstate = (float*)ws;      ws += (size_t)BB * HH * 6 * 4;      // 3072 B
    float* Svec = (float*)ws;         ws += (size_t)NQKV * 4;             // 768 B
    float* qb2 = (float*)ws;          ws += (size_t)NQKV * 4;             // 768 B

    hipFuncSetAttribute((const void*)k_qkv,
                        hipFuncAttributeMaxDynamicSharedMemorySize, 2 * BUF2);

    k_pre<<<304, 256, 0, stream>>>(qkv_w, nw, nb, qkv_b, out_w, W1, W2, Svec, qb2);
    k_qkv<<<NT / QB, 512, 2 * BUF2, stream>>>(x, W1, Svec, qb2, fm_w, fm_b, qfeat, kvpart);
    k_red<<<3, 256, 0, stream>>>(kvpart, kvstate);
    k_out<<<(NT / 32) * 2, 512, 0, stream>>>(qfeat, kvstate, W2, out_b, x, out);
}

// Round 15
// 120.828 us; speedup vs baseline: 1.0064x; 1.0064x over previous
//
#include <hip/hip_runtime.h>
#include <hip/hip_bf16.h>
#include <stdint.h>

typedef unsigned short ushort_t;

#define BB 4
#define SS 4096
#define DD 2048
#define KKC 64      // K channels
#define HH 32
#define NT (BB*SS)  // 16384 tokens
#define NQKV 192
#define QB 32       // tokens per k_qkv block

typedef float f32x4 __attribute__((ext_vector_type(4)));
typedef short s16x8 __attribute__((ext_vector_type(8)));

__device__ __forceinline__ ushort_t f2bf(float f) {
    union { float f; uint32_t u; } c; c.f = f;
    uint32_t u = c.u + 0x7fffu + ((c.u >> 16) & 1u);
    return (ushort_t)(u >> 16);
}
__device__ __forceinline__ float bf2f(ushort_t b) {
    union { uint32_t u; float f; } c; c.u = (uint32_t)b << 16; return c.f;
}

__device__ __forceinline__ uint32_t cvtpk(float lo, float hi) {
    uint32_t r;
    asm("v_cvt_pk_bf16_f32 %0, %1, %2" : "=v"(r) : "v"(lo), "v"(hi));
    return r;
}

// D = A(16x32) * B(32x16) + D, bf16 inputs, f32 acc.
// A lane map: row = l&15, k = 8*(l>>4)+e. B: col = l&15, k = 8*(l>>4)+e.
// C/D: col = l&15, row = 4*(l>>4)+reg.
__device__ __forceinline__ void mfma16(f32x4& d, s16x8 a, s16x8 b) {
    asm volatile("v_mfma_f32_16x16x32_bf16 %0, %1, %2, %0" : "+v"(d) : "v"(a), "v"(b));
}

// async global->LDS, 16B per lane; lds dest wave-uniform base (HW adds lane*16).
__device__ __forceinline__ void gload_lds16(const void* gsrc, void* ldst) {
    __builtin_amdgcn_global_load_lds(
        (const __attribute__((address_space(1))) unsigned int*)gsrc,
        (__attribute__((address_space(3))) unsigned int*)ldst,
        16, 0, 0);
}

// -------- merged weight pre-convert + per-col sums --------------------------
__global__ __launch_bounds__(256) void k_pre(
    const float* __restrict__ qkv_w, const float* __restrict__ nw,
    const float* __restrict__ nb, const float* __restrict__ qkv_b,
    const float* __restrict__ out_w,
    ushort_t* __restrict__ W1, ushort_t* __restrict__ W2,
    float* __restrict__ S, float* __restrict__ qb2) {
    int bid = blockIdx.x;
    if (bid < 256) {
        int E = bid * 256 + threadIdx.x;
        if (E < 49152) {
            int lane = E & 63; int rest = E >> 6;
            int f = rest % 12, g = rest / 12;
            int col = f * 16 + (lane & 15);
            int k0 = g * 32 + 8 * (lane >> 4);
            const float* src = qkv_w + (size_t)col * DD + k0;
            const float* wp = nw + k0;
            union { ushort_t u[8]; uint4 v; } cv;
            #pragma unroll
            for (int e = 0; e < 8; ++e) cv.u[e] = f2bf(src[e] * wp[e]);
            *(uint4*)(W1 + (size_t)E * 8) = cv.v;
        } else {
            int E2 = E - 49152;   // 16384 entries
            int lane = E2 & 63; int rest = E2 >> 6;
            int kk = rest & 1, F = rest >> 1;
            int n = F * 16 + (lane & 15);
            int k0 = kk * 32 + 8 * (lane >> 4);
            const float* src = out_w + (size_t)n * KKC + k0;
            union { ushort_t u[8]; uint4 v; } cv;
            #pragma unroll
            for (int e = 0; e < 8; ++e) cv.u[e] = f2bf(src[e]);
            *(uint4*)(W2 + (size_t)E2 * 8) = cv.v;
        }
    } else {
        int col = (bid - 256) * 4 + (threadIdx.x >> 6);   // 48 blocks -> 192 cols
        int lane = threadIdx.x & 63;
        float s = 0.f, qb = 0.f;
        for (int j = 0; j < 32; ++j) {
            int k = j * 64 + lane;
            float w = qkv_w[(size_t)col * DD + k];
            s += bf2f(f2bf(w * nw[k]));
            qb += nb[k] * w;
        }
        #pragma unroll
        for (int off = 32; off >= 1; off >>= 1) {
            s += __shfl_xor(s, off);
            qb += __shfl_xor(qb, off);
        }
        if (lane == 0) { S[col] = s; qb2[col] = qb + qkv_b[col]; }
    }
}

// ------- fused (LN-folded) QKV GEMM + stats + feature map + kv partials -----
// 32 tokens/block, grid 512 -> 2 blocks/CU. 512 thr = 8 waves:
// rg = wave&1 (16 rows), ch = wave>>1 (48 cols = 3 frags). BK=64, 32 steps.
// STATICALLY-DISTINCT double buffers (B0/X0, B1/X1 at compile-time LDS
// offsets) so the memory legalizer can disambiguate LDS-DMA vs ds_read and
// honor the counted vmcnt(4) (m201 template shape). Loop 2x-unrolled with
// literal buffer names; tail peeled with vmcnt(0).
__global__ __launch_bounds__(512, 4) void k_qkv(
    const float* __restrict__ x, const ushort_t* __restrict__ W1,
    const float* __restrict__ S, const float* __restrict__ qb2,
    const float* __restrict__ fm_w, const float* __restrict__ fm_b,
    float* __restrict__ qfeat,          // [NT][64]
    float* __restrict__ kvpart)         // [512 blocks][192]
{
    __shared__ __align__(16) union {
        struct {
            ushort_t B0[1536 * 8];      // 24576 B  (offset 0)
            float    X0[QB * 64];       //  8192 B  (offset 24576)
            ushort_t B1[1536 * 8];      // 24576 B  (offset 32768)
            float    X1[QB * 64];       //  8192 B  (offset 57344)
        } s;
        float cep[QB][NQKV];            // 24576 B overlay (post-drain only)
    } sm;                                // 65536 B
    __shared__ float kvred[32][16][6];   // 12288 B
    __shared__ float stats4[4][QB][2];   // 1024 B
    __shared__ float stats[QB][2];       // 256 B

    const int tid = threadIdx.x;
    const int wave = tid >> 6, lane = tid & 63;
    const int rg = wave & 1, ch = wave >> 1;
    const int m0 = blockIdx.x * QB;

    const int rloc = rg * 16 + (lane & 15);
    const int q4 = lane >> 4;
    const int swz = rloc & 7;
    const int fbase = ch * 3;

    // x staging: 512 16B-entries/step, 1 per thread
    const int row0 = tid >> 4;
    const int slot0 = (tid & 15) ^ (row0 & 7);      // pre-swizzled source
    const size_t xg0 = (size_t)(m0 + row0) * DD + slot0 * 4;
    const int xd0 = wave * 1024;                    // wave-uniform byte base

    f32x4 acc[3];
    #pragma unroll
    for (int j = 0; j < 3; ++j) acc[j] = (f32x4){0.f, 0.f, 0.f, 0.f};
    float st1 = 0.f, st2 = 0.f;

#define STAGE(T, BARR, XARR) do { \
        _Pragma("unroll") \
        for (int i_ = 0; i_ < 3; ++i_) { \
            int eb_ = i_ * 512 + wave * 64; \
            gload_lds16((const char*)W1 + ((size_t)(T) * 1536 + eb_ + lane) * 16, \
                        (char*)(BARR) + eb_ * 16); \
        } \
        gload_lds16(x + xg0 + (size_t)(T) * 64, (char*)(XARR) + xd0); \
    } while (0)

#define STEP_BODY(BARR, XARR, T) do { \
        const s16x8* bb_ = (const s16x8*)(BARR); \
        const float* xb_ = (const float*)(XARR) + rloc * 64; \
        const bool doStats_ = (((T) & 3) == ch); \
        s16x8 afr0_, afr1_; \
        { \
            int sg0_ = 2 * q4, sg1_ = 8 + 2 * q4; \
            float4 a0_ = *(const float4*)(xb_ + ((sg0_    ) ^ swz) * 4); \
            float4 a1_ = *(const float4*)(xb_ + ((sg0_ + 1) ^ swz) * 4); \
            float4 b0_ = *(const float4*)(xb_ + ((sg1_    ) ^ swz) * 4); \
            float4 b1_ = *(const float4*)(xb_ + ((sg1_ + 1) ^ swz) * 4); \
            if (doStats_) { \
                st1 += a0_.x+a0_.y+a0_.z+a0_.w + a1_.x+a1_.y+a1_.z+a1_.w \
                     + b0_.x+b0_.y+b0_.z+b0_.w + b1_.x+b1_.y+b1_.z+b1_.w; \
                st2 += a0_.x*a0_.x+a0_.y*a0_.y+a0_.z*a0_.z+a0_.w*a0_.w \
                     + a1_.x*a1_.x+a1_.y*a1_.y+a1_.z*a1_.z+a1_.w*a1_.w \
                     + b0_.x*b0_.x+b0_.y*b0_.y+b0_.z*b0_.z+b0_.w*b0_.w \
                     + b1_.x*b1_.x+b1_.y*b1_.y+b1_.z*b1_.z+b1_.w*b1_.w; \
            } \
            union { uint32_t w[4]; s16x8 v; } c0_, c1_; \
            c0_.w[0] = cvtpk(a0_.x, a0_.y); c0_.w[1] = cvtpk(a0_.z, a0_.w); \
            c0_.w[2] = cvtpk(a1_.x, a1_.y); c0_.w[3] = cvtpk(a1_.z, a1_.w); \
            c1_.w[0] = cvtpk(b0_.x, b0_.y); c1_.w[1] = cvtpk(b0_.z, b0_.w); \
            c1_.w[2] = cvtpk(b1_.x, b1_.y); c1_.w[3] = cvtpk(b1_.z, b1_.w); \
            afr0_ = c0_.v; afr1_ = c1_.v; \
        } \
        __builtin_amdgcn_s_setprio(1); \
        _Pragma("unroll") \
        for (int j_ = 0; j_ < 3; ++j_) { \
            s16x8 w0_ = bb_[(fbase + j_) * 64 + lane]; \
            s16x8 w1_ = bb_[(12 + fbase + j_) * 64 + lane]; \
            mfma16(acc[j_], afr0_, w0_); \
            mfma16(acc[j_], afr1_, w1_); \
        } \
        __builtin_amdgcn_s_setprio(0); \
    } while (0)

#define WAITN(N) asm volatile("s_waitcnt vmcnt(" #N ")" ::: "memory")

    STAGE(0, sm.s.B0, sm.s.X0);
    for (int tp = 0; tp < 15; ++tp) {
        const int t0 = 2 * tp, t1 = t0 + 1;
        STAGE(t1, sm.s.B1, sm.s.X1);
        WAITN(4);                                  // stage(t0) landed
        __builtin_amdgcn_s_barrier();
        __builtin_amdgcn_sched_barrier(0);
        STEP_BODY(sm.s.B0, sm.s.X0, t0);
        __builtin_amdgcn_s_barrier();              // buf0 reads done
        STAGE(t1 + 1, sm.s.B0, sm.s.X0);
        WAITN(4);                                  // stage(t1) landed
        __builtin_amdgcn_s_barrier();
        __builtin_amdgcn_sched_barrier(0);
        STEP_BODY(sm.s.B1, sm.s.X1, t1);
        __builtin_amdgcn_s_barrier();              // buf1 reads done
    }
    // t = 30 (staged in buf0), t = 31
    STAGE(31, sm.s.B1, sm.s.X1);
    WAITN(4);
    __builtin_amdgcn_s_barrier();
    __builtin_amdgcn_sched_barrier(0);
    STEP_BODY(sm.s.B0, sm.s.X0, 30);
    __builtin_amdgcn_s_barrier();
    WAITN(0);                                      // stage(31) landed
    __builtin_amdgcn_s_barrier();
    __builtin_amdgcn_sched_barrier(0);
    STEP_BODY(sm.s.B1, sm.s.X1, 31);

    // ---- stats: reduce q4 groups, publish per-ch partials
    st1 += __shfl_xor(st1, 16); st2 += __shfl_xor(st2, 16);
    st1 += __shfl_xor(st1, 32); st2 += __shfl_xor(st2, 32);
    if (lane < 16) { stats4[ch][rloc][0] = st1; stats4[ch][rloc][1] = st2; }
    __syncthreads();    // all LDS reads consumed; stats4 visible

    // ---- C -> LDS overlay (clobbers staging bufs; safe post-drain)
    #pragma unroll
    for (int j = 0; j < 3; ++j) {
        int col = (fbase + j) * 16 + (lane & 15);
        int rbase = rg * 16 + (lane >> 4) * 4;
        #pragma unroll
        for (int r = 0; r < 4; ++r)
            sm.cep[rbase + r][col] = acc[j][r];
    }
    if (tid < QB) {
        float s1 = stats4[0][tid][0] + stats4[1][tid][0] + stats4[2][tid][0] + stats4[3][tid][0];
        float s2 = stats4[0][tid][1] + stats4[1][tid][1] + stats4[2][tid][1] + stats4[3][tid][1];
        float mu = s1 * (1.f / DD);
        float var = s2 * (1.f / DD) - mu * mu;
        stats[tid][0] = mu;
        stats[tid][1] = rsqrtf(var + 1e-5f);
    }
    __syncthreads();

    // ---- per (token, head): LN-affine + feature map + qfeat + kv partials
    const int h = tid & 31, gg = tid >> 5;     // gg 0..15, 2 tokens each
    const float fm00 = fm_w[0], fm01 = fm_w[1], fm10 = fm_w[2], fm11 = fm_w[3];
    const float fb0 = fm_b[0], fb1 = fm_b[1];
    const float Sq0 = S[2*h],      Sq1 = S[2*h+1],      cq0 = qb2[2*h],      cq1 = qb2[2*h+1];
    const float Sk0 = S[64+2*h],   Sk1 = S[64+2*h+1],   ck0 = qb2[64+2*h],   ck1 = qb2[64+2*h+1];
    const float Sv0 = S[128+2*h],  Sv1 = S[128+2*h+1],  cv0 = qb2[128+2*h],  cv1 = qb2[128+2*h+1];
    float kv00=0, kv01=0, kv10=0, kv11=0, ks0=0, ks1=0;
    #pragma unroll
    for (int i = 0; i < 2; ++i) {
        int tt = gg * 2 + i;
        float mu = stats[tt][0], rs = stats[tt][1];
        float f = mu * rs;
        float q0 = rs * sm.cep[tt][2*h]      - f * Sq0 + cq0;
        float q1 = rs * sm.cep[tt][2*h+1]    - f * Sq1 + cq1;
        float k0 = rs * sm.cep[tt][64+2*h]   - f * Sk0 + ck0;
        float k1 = rs * sm.cep[tt][64+2*h+1] - f * Sk1 + ck1;
        float v0 = rs * sm.cep[tt][128+2*h]  - f * Sv0 + cv0;
        float v1 = rs * sm.cep[tt][128+2*h+1]- f * Sv1 + cv1;
        float qp0 = fmaxf(fm00*q0 + fm01*q1 + fb0, 0.f);
        float qp1 = fmaxf(fm10*q0 + fm11*q1 + fb1, 0.f);
        float kp0 = fmaxf(fm00*k0 + fm01*k1 + fb0, 0.f);
        float kp1 = fmaxf(fm10*k0 + fm11*k1 + fb1, 0.f);
        *(float2*)(qfeat + (size_t)(m0 + tt) * KKC + 2*h) = make_float2(qp0, qp1);
        kv00 += kp0*v0; kv01 += kp0*v1; kv10 += kp1*v0; kv11 += kp1*v1;
        ks0 += kp0; ks1 += kp1;
    }
    kvred[h][gg][0]=kv00; kvred[h][gg][1]=kv01; kvred[h][gg][2]=kv10;
    kvred[h][gg][3]=kv11; kvred[h][gg][4]=ks0;  kvred[h][gg][5]=ks1;
    __syncthreads();
    if (tid < 192) {
        int h2 = tid / 6, j = tid % 6;
        float s = 0.f;
        #pragma unroll
        for (int g2 = 0; g2 < 16; ++g2) s += kvred[h2][g2][j];
        kvpart[(size_t)blockIdx.x * 192 + tid] = s;
    }
#undef STAGE
#undef STEP_BODY
#undef WAITN
}

// ---------------- reduce kv partials (deterministic) ----------------
__global__ void k_red(const float* __restrict__ kvpart, float* __restrict__ kvstate) {
    int idx = blockIdx.x * 256 + threadIdx.x;   // 768 = B*H*6
    if (idx >= BB * HH * 6) return;
    int b = idx / 192, r = idx % 192;
    float s = 0.f;
    for (int blk = 0; blk < 128; ++blk)
        s += kvpart[(size_t)(b * 128 + blk) * 192 + r];
    kvstate[idx] = s;  // [b][h][6]
}

// ---------------- out-projection GEMM (attn inline) + residual -------------
#define CEP_STRIDE 260
__global__ __launch_bounds__(512, 4) void k_out(
    const float* __restrict__ qfeat, const float* __restrict__ kvstate,
    const ushort_t* __restrict__ W2, const float* __restrict__ out_b,
    const float* __restrict__ x, float* __restrict__ out) {
    __shared__ float skv[192];
    __shared__ __align__(16) float cep[32 * CEP_STRIDE];   // 33280 B
    const int tid = threadIdx.x, wave = tid >> 6, lane = tid & 63;
    const int rg = wave & 1, cq = wave >> 1;
    const int mb = blockIdx.x >> 1, nb = blockIdx.x & 1;
    const int m0 = mb * 32;
    const int n0 = nb * 1024;
    const int b = m0 >> 12;
    if (tid < 192) skv[tid] = kvstate[b * 192 + tid];

    const int arow = m0 + rg * 16 + (lane & 15);
    const int ksub = 8 * (lane >> 4);
    float4 qa0 = *(const float4*)(qfeat + (size_t)arow * KKC + ksub);
    float4 qa1 = *(const float4*)(qfeat + (size_t)arow * KKC + ksub + 4);
    float4 qb0 = *(const float4*)(qfeat + (size_t)arow * KKC + 32 + ksub);
    float4 qb1 = *(const float4*)(qfeat + (size_t)arow * KKC + 32 + ksub + 4);
    __syncthreads();

    union { ushort_t u[8]; s16x8 v; } ca, cb;
    {
        float qs[8] = {qa0.x,qa0.y,qa0.z,qa0.w,qa1.x,qa1.y,qa1.z,qa1.w};
        float rs[8] = {qb0.x,qb0.y,qb0.z,qb0.w,qb1.x,qb1.y,qb1.z,qb1.w};
        #pragma unroll
        for (int e = 0; e < 8; e += 2) {
            int h = (ksub + e) >> 1;
            const float* kv = skv + h * 6;
            float q0 = qs[e], q1 = qs[e+1];
            float inv = 1.f / (q0 * kv[4] + q1 * kv[5] + 1e-8f);
            ca.u[e]   = f2bf((q0 * kv[0] + q1 * kv[2]) * inv);
            ca.u[e+1] = f2bf((q0 * kv[1] + q1 * kv[3]) * inv);
            const float* kw = skv + (h + 16) * 6;
            float p0 = rs[e], p1 = rs[e+1];
            float iw = 1.f / (p0 * kw[4] + p1 * kw[5] + 1e-8f);
            cb.u[e]   = f2bf((p0 * kw[0] + p1 * kw[2]) * iw);
            cb.u[e+1] = f2bf((p0 * kw[1] + p1 * kw[3]) * iw);
        }
    }

    f32x4 acc[16];
    #pragma unroll
    for (int j = 0; j < 16; ++j) acc[j] = (f32x4){0.f, 0.f, 0.f, 0.f};
    #pragma unroll
    for (int j = 0; j < 16; ++j) {
        int Fg = (n0 >> 4) + cq + 4 * j;
        s16x8 b0 = *(const s16x8*)(W2 + ((size_t)(Fg * 2 + 0) * 64 + lane) * 8);
        s16x8 b1 = *(const s16x8*)(W2 + ((size_t)(Fg * 2 + 1) * 64 + lane) * 8);
        mfma16(acc[j], ca.v, b0);
        mfma16(acc[j], cb.v, b1);
    }

    const int wrow = rg * 16 + 4 * (lane >> 4);
    #pragma unroll
    for (int n = 0; n < 4; ++n) {
        #pragma unroll
        for (int i = 0; i < 4; ++i) {
            int col = cq * 16 + i * 64 + (lane & 15);
            #pragma unroll
            for (int r = 0; r < 4; ++r)
                cep[(wrow + r) * CEP_STRIDE + col] = acc[4 * n + i][r];
        }
        __syncthreads();
        #pragma unroll
        for (int p = 0; p < 4; ++p) {
            int row = p * 8 + (tid >> 6);
            int c4 = tid & 63;
            float4 c = *(const float4*)(cep + row * CEP_STRIDE + c4 * 4);
            int gcol = n0 + n * 256 + c4 * 4;
            size_t off = (size_t)(m0 + row) * DD + gcol;
            float4 xr = *(const float4*)(x + off);
            float4 ob = *(const float4*)(out_b + gcol);
            float4 o;
            o.x = c.x + ob.x + xr.x; o.y = c.y + ob.y + xr.y;
            o.z = c.z + ob.z + xr.z; o.w = c.w + ob.w + xr.w;
            *(float4*)(out + off) = o;
        }
        __syncthreads();
    }
}

extern "C" void kernel_launch(void* const* d_in, const int* in_sizes, int n_in,
                              void* d_out, int out_size, void* d_ws, size_t ws_size,
                              hipStream_t stream) {
    const float* x     = (const float*)d_in[0];
    const float* nw    = (const float*)d_in[1];
    const float* nb    = (const float*)d_in[2];
    const float* qkv_w = (const float*)d_in[3];
    const float* qkv_b = (const float*)d_in[4];
    const float* fm_w  = (const float*)d_in[5];
    const float* fm_b  = (const float*)d_in[6];
    const float* out_w = (const float*)d_in[7];
    const float* out_b = (const float*)d_in[8];
    float* out = (float*)d_out;

    char* ws = (char*)d_ws;
    ushort_t* W1 = (ushort_t*)ws;     ws += (size_t)NQKV * DD * 2;        // 786432 B
    ushort_t* W2 = (ushort_t*)ws;     ws += (size_t)DD * KKC * 2;         // 262144 B
    float* qfeat = (float*)ws;        ws += (size_t)NT * KKC * 4;         // 4 MiB
    float* kvpart = (float*)ws;       ws += (size_t)512 * 192 * 4;        // 393216 B
    float* kvstate = (float*)ws;      ws += (size_t)BB * HH * 6 * 4;      // 3072 B
    float* Svec = (float*)ws;         ws += (size_t)NQKV * 4;             // 768 B
    float* qb2 = (float*)ws;          ws += (size_t)NQKV * 4;             // 768 B

    k_pre<<<304, 256, 0, stream>>>(qkv_w, nw, nb, qkv_b, out_w, W1, W2, Svec, qb2);
    k_qkv<<<NT / QB, 512, 0, stream>>>(x, W1, Svec, qb2, fm_w, fm_b, qfeat, kvpart);
    k_red<<<3, 256, 0, stream>>>(kvpart, kvstate);
    k_out<<<(NT / 32) * 2, 512, 0, stream>>>(qfeat, kvstate, W2, out_b, x, out);
}

// Round 16
// 119.274 us; speedup vs baseline: 1.0195x; 1.0130x over previous
//
#include <hip/hip_runtime.h>
#include <hip/hip_bf16.h>
#include <stdint.h>

typedef unsigned short ushort_t;

#define BB 4
#define SS 4096
#define DD 2048
#define KKC 64      // K channels
#define HH 32
#define NT (BB*SS)  // 16384 tokens
#define NQKV 192
#define QB 64       // tokens per k_qkv block
#define BK 128      // K per step -> 16 steps

typedef float f32x4 __attribute__((ext_vector_type(4)));
typedef short s16x8 __attribute__((ext_vector_type(8)));

__device__ __forceinline__ ushort_t f2bf(float f) {
    union { float f; uint32_t u; } c; c.f = f;
    uint32_t u = c.u + 0x7fffu + ((c.u >> 16) & 1u);
    return (ushort_t)(u >> 16);
}
__device__ __forceinline__ float bf2f(ushort_t b) {
    union { uint32_t u; float f; } c; c.u = (uint32_t)b << 16; return c.f;
}

__device__ __forceinline__ uint32_t cvtpk(float lo, float hi) {
    uint32_t r;
    asm("v_cvt_pk_bf16_f32 %0, %1, %2" : "=v"(r) : "v"(lo), "v"(hi));
    return r;
}

// D = A(16x32) * B(32x16) + D, bf16 inputs, f32 acc.
// A lane map: row = l&15, k = 8*(l>>4)+e. B: col = l&15, k = 8*(l>>4)+e.
// C/D: col = l&15, row = 4*(l>>4)+reg.
__device__ __forceinline__ void mfma16(f32x4& d, s16x8 a, s16x8 b) {
    asm volatile("v_mfma_f32_16x16x32_bf16 %0, %1, %2, %0" : "+v"(d) : "v"(a), "v"(b));
}

// async global->LDS, 16B per lane; lds dest wave-uniform base (HW adds lane*16).
__device__ __forceinline__ void gload_lds16(const void* gsrc, void* ldst) {
    __builtin_amdgcn_global_load_lds(
        (const __attribute__((address_space(1))) unsigned int*)gsrc,
        (__attribute__((address_space(3))) unsigned int*)ldst,
        16, 0, 0);
}

// -------- merged weight pre-convert + per-col sums --------------------------
// W1' entry E (16B): lane=E&63, f=(E>>6)%12, g=(E>>6)/12 (g=kblk-of-32, 0..63)
//   col=f*16+(lane&15); k0=g*32+8*(lane>>4); holds qkv_w[col][k]*norm_w[k]
__global__ __launch_bounds__(256) void k_pre(
    const float* __restrict__ qkv_w, const float* __restrict__ nw,
    const float* __restrict__ nb, const float* __restrict__ qkv_b,
    const float* __restrict__ out_w,
    ushort_t* __restrict__ W1, ushort_t* __restrict__ W2,
    float* __restrict__ S, float* __restrict__ qb2) {
    int bid = blockIdx.x;
    if (bid < 256) {
        int E = bid * 256 + threadIdx.x;
        if (E < 49152) {
            int lane = E & 63; int rest = E >> 6;
            int f = rest % 12, g = rest / 12;
            int col = f * 16 + (lane & 15);
            int k0 = g * 32 + 8 * (lane >> 4);
            const float* src = qkv_w + (size_t)col * DD + k0;
            const float* wp = nw + k0;
            union { ushort_t u[8]; uint4 v; } cv;
            #pragma unroll
            for (int e = 0; e < 8; ++e) cv.u[e] = f2bf(src[e] * wp[e]);
            *(uint4*)(W1 + (size_t)E * 8) = cv.v;
        } else {
            int E2 = E - 49152;   // 16384 entries
            int lane = E2 & 63; int rest = E2 >> 6;
            int kk = rest & 1, F = rest >> 1;
            int n = F * 16 + (lane & 15);
            int k0 = kk * 32 + 8 * (lane >> 4);
            const float* src = out_w + (size_t)n * KKC + k0;
            union { ushort_t u[8]; uint4 v; } cv;
            #pragma unroll
            for (int e = 0; e < 8; ++e) cv.u[e] = f2bf(src[e]);
            *(uint4*)(W2 + (size_t)E2 * 8) = cv.v;
        }
    } else {
        int col = (bid - 256) * 4 + (threadIdx.x >> 6);   // 48 blocks -> 192 cols
        int lane = threadIdx.x & 63;
        float s = 0.f, qb = 0.f;
        for (int j = 0; j < 32; ++j) {
            int k = j * 64 + lane;
            float w = qkv_w[(size_t)col * DD + k];
            s += bf2f(f2bf(w * nw[k]));
            qb += nb[k] * w;
        }
        #pragma unroll
        for (int off = 32; off >= 1; off >>= 1) {
            s += __shfl_xor(s, off);
            qb += __shfl_xor(qb, off);
        }
        if (lane == 0) { S[col] = s; qb2[col] = qb + qkv_b[col]; }
    }
}

// ------- fused (LN-folded) QKV GEMM + stats + feature map + kv partials -----
// QB=64 tokens/block, BK=128 -> 16 steps. grid 256 (1 block/CU), 512 thr =
// 8 waves: rg = wave&1 (rows rg*32..+31, 2 rowfrags), ch = wave>>1 (48 cols).
// Double buffer: B (48KB, global_load_lds DMA) + x as BF16 (16KB, reg-staged:
// f32 global->reg early, cvtpk + swizzled ds_write late = T14). Counted
// vmcnt: WAITN(6) for x-regs, WAITN(0) for own B-DMA before the single
// per-step barrier. Exact f32 LN stats accumulated in the staging path.
__global__ __launch_bounds__(512, 2) void k_qkv(
    const float* __restrict__ x, const ushort_t* __restrict__ W1,
    const float* __restrict__ S, const float* __restrict__ qb2,
    const float* __restrict__ fm_w, const float* __restrict__ fm_b,
    float* __restrict__ qfeat,          // [NT][64]
    float* __restrict__ kvpart)         // [256 blocks][192]
{
    __shared__ __align__(16) union {
        struct {
            ushort_t B0[3072 * 8];      // 49152 B
            ushort_t X0[QB * BK];       // 16384 B (bf16 x tile)
            ushort_t B1[3072 * 8];      // 49152 B
            ushort_t X1[QB * BK];       // 16384 B
        } s;                             // 131072 B
        float cep[QB][NQKV];            // 49152 B overlay (post-loop)
    } sm;
    __shared__ float kvred[32][16][6];   // 12288 B
    __shared__ float stats[QB][2];       // 512 B

    const int tid = threadIdx.x;
    const int wave = tid >> 6, lane = tid & 63;
    const int rg = wave & 1, ch = wave >> 1;
    const int m0 = blockIdx.x * QB;
    const int l15 = lane & 15, q4 = lane >> 4;

    // ---- x staging geometry: 1024 16B-entries/step, 2 per thread
    const int row0 = tid >> 4;          // 0..31
    const int sl0 = tid & 15;
    const int row1 = row0 + 32;
    const float* xs0 = x + (size_t)(m0 + row0) * DD + sl0 * 8;
    const float* xs1 = x + (size_t)(m0 + row1) * DD + sl0 * 8;
    const int wb0 = row0 * 256 + ((sl0 ^ (row0 & 7)) << 4);
    const int wb1 = row1 * 256 + ((sl0 ^ (row1 & 7)) << 4);

    f32x4 acc[2][3];
    #pragma unroll
    for (int rf = 0; rf < 2; ++rf)
        #pragma unroll
        for (int f = 0; f < 3; ++f) acc[rf][f] = (f32x4){0.f, 0.f, 0.f, 0.f};
    float st1[2] = {0.f, 0.f}, st2[2] = {0.f, 0.f};

    float4 xa[4];

#define XISSUE(T) do { \
        xa[0] = *(const float4*)(xs0 + (size_t)(T) * BK); \
        xa[1] = *(const float4*)(xs0 + (size_t)(T) * BK + 4); \
        xa[2] = *(const float4*)(xs1 + (size_t)(T) * BK); \
        xa[3] = *(const float4*)(xs1 + (size_t)(T) * BK + 4); \
    } while (0)

#define BSTAGE(T, BARR) do { \
        _Pragma("unroll") \
        for (int i_ = 0; i_ < 6; ++i_) { \
            int eb_ = i_ * 512 + wave * 64; \
            gload_lds16((const char*)W1 + ((size_t)(T) * 3072 + eb_ + lane) * 16, \
                        (char*)(BARR) + eb_ * 16); \
        } \
    } while (0)

#define CVTW(XARR) do { \
        st1[0] += xa[0].x+xa[0].y+xa[0].z+xa[0].w + xa[1].x+xa[1].y+xa[1].z+xa[1].w; \
        st2[0] += xa[0].x*xa[0].x+xa[0].y*xa[0].y+xa[0].z*xa[0].z+xa[0].w*xa[0].w \
                + xa[1].x*xa[1].x+xa[1].y*xa[1].y+xa[1].z*xa[1].z+xa[1].w*xa[1].w; \
        st1[1] += xa[2].x+xa[2].y+xa[2].z+xa[2].w + xa[3].x+xa[3].y+xa[3].z+xa[3].w; \
        st2[1] += xa[2].x*xa[2].x+xa[2].y*xa[2].y+xa[2].z*xa[2].z+xa[2].w*xa[2].w \
                + xa[3].x*xa[3].x+xa[3].y*xa[3].y+xa[3].z*xa[3].z+xa[3].w*xa[3].w; \
        uint4 w0_, w1_; \
        w0_.x = cvtpk(xa[0].x, xa[0].y); w0_.y = cvtpk(xa[0].z, xa[0].w); \
        w0_.z = cvtpk(xa[1].x, xa[1].y); w0_.w = cvtpk(xa[1].z, xa[1].w); \
        w1_.x = cvtpk(xa[2].x, xa[2].y); w1_.y = cvtpk(xa[2].z, xa[2].w); \
        w1_.z = cvtpk(xa[3].x, xa[3].y); w1_.w = cvtpk(xa[3].z, xa[3].w); \
        *(uint4*)((char*)(XARR) + wb0) = w0_; \
        *(uint4*)((char*)(XARR) + wb1) = w1_; \
    } while (0)

#define STEP_BODY(BARR, XARR) do { \
        const char* bp_ = (const char*)(BARR); \
        const char* xp_ = (const char*)(XARR); \
        const int r0_ = rg * 32 + l15, r1_ = r0_ + 16; \
        _Pragma("unroll") \
        for (int kb_ = 0; kb_ < 4; ++kb_) { \
            s16x8 a0_ = *(const s16x8*)(xp_ + r0_ * 256 + (((kb_ * 4 + q4) ^ (r0_ & 7)) << 4)); \
            s16x8 a1_ = *(const s16x8*)(xp_ + r1_ * 256 + (((kb_ * 4 + q4) ^ (r1_ & 7)) << 4)); \
            __builtin_amdgcn_s_setprio(1); \
            _Pragma("unroll") \
            for (int f_ = 0; f_ < 3; ++f_) { \
                s16x8 b_ = *(const s16x8*)(bp_ + ((kb_ * 12 + ch * 3 + f_) * 64 + lane) * 16); \
                mfma16(acc[0][f_], a0_, b_); \
                mfma16(acc[1][f_], a1_, b_); \
            } \
            __builtin_amdgcn_s_setprio(0); \
        } \
    } while (0)

#define WAITN(N) asm volatile("s_waitcnt vmcnt(" #N ")" ::: "memory")
#define LGKM0()  asm volatile("s_waitcnt lgkmcnt(0)" ::: "memory")
#define BARR_()  do { __builtin_amdgcn_s_barrier(); __builtin_amdgcn_sched_barrier(0); } while (0)

// one pipelined step: read CUR buffers for step T, stage T+1 into NX buffers
#define ITER(T, CB, CX, NB_, NX_) do { \
        XISSUE((T) + 1); \
        BSTAGE((T) + 1, NB_); \
        STEP_BODY(CB, CX); \
        WAITN(6); \
        CVTW(NX_); \
        LGKM0(); \
        WAITN(0); \
        BARR_(); \
    } while (0)

    // prologue: stage step 0
    XISSUE(0);
    BSTAGE(0, sm.s.B0);
    WAITN(6);
    CVTW(sm.s.X0);
    LGKM0();
    WAITN(0);
    BARR_();

    #pragma unroll
    for (int tp = 0; tp < 7; ++tp) {
        ITER(2 * tp,     sm.s.B0, sm.s.X0, sm.s.B1, sm.s.X1);
        ITER(2 * tp + 1, sm.s.B1, sm.s.X1, sm.s.B0, sm.s.X0);
    }
    ITER(14, sm.s.B0, sm.s.X0, sm.s.B1, sm.s.X1);
    STEP_BODY(sm.s.B1, sm.s.X1);        // step 15, nothing left to stage

    // ---- exact f32 LN stats: each thread owns rows (row0, row1) slices
    #pragma unroll
    for (int j = 0; j < 2; ++j) {
        st1[j] += __shfl_xor(st1[j], 1); st2[j] += __shfl_xor(st2[j], 1);
        st1[j] += __shfl_xor(st1[j], 2); st2[j] += __shfl_xor(st2[j], 2);
        st1[j] += __shfl_xor(st1[j], 4); st2[j] += __shfl_xor(st2[j], 4);
        st1[j] += __shfl_xor(st1[j], 8); st2[j] += __shfl_xor(st2[j], 8);
    }
    if (l15 == 0) {
        #pragma unroll
        for (int j = 0; j < 2; ++j) {
            int row = wave * 4 + q4 + j * 32;
            float mu = st1[j] * (1.f / DD);
            float var = st2[j] * (1.f / DD) - mu * mu;
            stats[row][0] = mu;
            stats[row][1] = rsqrtf(var + 1e-5f);
        }
    }

    // ---- C -> cep overlay (overlays B0/X0; step-15 readers used B1/X1)
    #pragma unroll
    for (int rf = 0; rf < 2; ++rf) {
        int rbase = rg * 32 + rf * 16 + q4 * 4;
        #pragma unroll
        for (int f = 0; f < 3; ++f) {
            int col = (ch * 3 + f) * 16 + l15;
            #pragma unroll
            for (int r = 0; r < 4; ++r)
                sm.cep[rbase + r][col] = acc[rf][f][r];
        }
    }
    __syncthreads();

    // ---- per (token, head): LN-affine + feature map + qfeat + kv partials
    const int h = tid & 31, gg = tid >> 5;     // gg 0..15, 4 tokens each
    const float fm00 = fm_w[0], fm01 = fm_w[1], fm10 = fm_w[2], fm11 = fm_w[3];
    const float fb0 = fm_b[0], fb1 = fm_b[1];
    const float Sq0 = S[2*h],      Sq1 = S[2*h+1],      cq0 = qb2[2*h],      cq1 = qb2[2*h+1];
    const float Sk0 = S[64+2*h],   Sk1 = S[64+2*h+1],   ck0 = qb2[64+2*h],   ck1 = qb2[64+2*h+1];
    const float Sv0 = S[128+2*h],  Sv1 = S[128+2*h+1],  cv0 = qb2[128+2*h],  cv1 = qb2[128+2*h+1];
    float kv00=0, kv01=0, kv10=0, kv11=0, ks0=0, ks1=0;
    #pragma unroll
    for (int i = 0; i < 4; ++i) {
        int tt = gg * 4 + i;
        float mu = stats[tt][0], rs = stats[tt][1];
        float f = mu * rs;
        float q0 = rs * sm.cep[tt][2*h]      - f * Sq0 + cq0;
        float q1 = rs * sm.cep[tt][2*h+1]    - f * Sq1 + cq1;
        float k0 = rs * sm.cep[tt][64+2*h]   - f * Sk0 + ck0;
        float k1 = rs * sm.cep[tt][64+2*h+1] - f * Sk1 + ck1;
        float v0 = rs * sm.cep[tt][128+2*h]  - f * Sv0 + cv0;
        float v1 = rs * sm.cep[tt][128+2*h+1]- f * Sv1 + cv1;
        float qp0 = fmaxf(fm00*q0 + fm01*q1 + fb0, 0.f);
        float qp1 = fmaxf(fm10*q0 + fm11*q1 + fb1, 0.f);
        float kp0 = fmaxf(fm00*k0 + fm01*k1 + fb0, 0.f);
        float kp1 = fmaxf(fm10*k0 + fm11*k1 + fb1, 0.f);
        *(float2*)(qfeat + (size_t)(m0 + tt) * KKC + 2*h) = make_float2(qp0, qp1);
        kv00 += kp0*v0; kv01 += kp0*v1; kv10 += kp1*v0; kv11 += kp1*v1;
        ks0 += kp0; ks1 += kp1;
    }
    kvred[h][gg][0]=kv00; kvred[h][gg][1]=kv01; kvred[h][gg][2]=kv10;
    kvred[h][gg][3]=kv11; kvred[h][gg][4]=ks0;  kvred[h][gg][5]=ks1;
    __syncthreads();
    if (tid < 192) {
        int h2 = tid / 6, j = tid % 6;
        float s = 0.f;
        #pragma unroll
        for (int g2 = 0; g2 < 16; ++g2) s += kvred[h2][g2][j];
        kvpart[(size_t)blockIdx.x * 192 + tid] = s;
    }
#undef XISSUE
#undef BSTAGE
#undef CVTW
#undef STEP_BODY
#undef WAITN
#undef LGKM0
#undef BARR_
#undef ITER
}

// ---------------- reduce kv partials (deterministic) ----------------
__global__ void k_red(const float* __restrict__ kvpart, float* __restrict__ kvstate) {
    int idx = blockIdx.x * 256 + threadIdx.x;   // 768 = B*H*6
    if (idx >= BB * HH * 6) return;
    int b = idx / 192, r = idx % 192;
    float s = 0.f;
    for (int blk = 0; blk < 64; ++blk)
        s += kvpart[(size_t)(b * 64 + blk) * 192 + r];
    kvstate[idx] = s;  // [b][h][6]
}

// ---------------- out-projection GEMM (attn inline) + residual -------------
#define CEP_STRIDE 260
__global__ __launch_bounds__(512, 4) void k_out(
    const float* __restrict__ qfeat, const float* __restrict__ kvstate,
    const ushort_t* __restrict__ W2, const float* __restrict__ out_b,
    const float* __restrict__ x, float* __restrict__ out) {
    __shared__ float skv[192];
    __shared__ __align__(16) float cep[32 * CEP_STRIDE];   // 33280 B
    const int tid = threadIdx.x, wave = tid >> 6, lane = tid & 63;
    const int rg = wave & 1, cq = wave >> 1;
    const int mb = blockIdx.x >> 1, nb = blockIdx.x & 1;
    const int m0 = mb * 32;
    const int n0 = nb * 1024;
    const int b = m0 >> 12;
    if (tid < 192) skv[tid] = kvstate[b * 192 + tid];

    const int arow = m0 + rg * 16 + (lane & 15);
    const int ksub = 8 * (lane >> 4);
    float4 qa0 = *(const float4*)(qfeat + (size_t)arow * KKC + ksub);
    float4 qa1 = *(const float4*)(qfeat + (size_t)arow * KKC + ksub + 4);
    float4 qb0 = *(const float4*)(qfeat + (size_t)arow * KKC + 32 + ksub);
    float4 qb1 = *(const float4*)(qfeat + (size_t)arow * KKC + 32 + ksub + 4);
    __syncthreads();

    union { ushort_t u[8]; s16x8 v; } ca, cb;
    {
        float qs[8] = {qa0.x,qa0.y,qa0.z,qa0.w,qa1.x,qa1.y,qa1.z,qa1.w};
        float rs[8] = {qb0.x,qb0.y,qb0.z,qb0.w,qb1.x,qb1.y,qb1.z,qb1.w};
        #pragma unroll
        for (int e = 0; e < 8; e += 2) {
            int h = (ksub + e) >> 1;
            const float* kv = skv + h * 6;
            float q0 = qs[e], q1 = qs[e+1];
            float inv = 1.f / (q0 * kv[4] + q1 * kv[5] + 1e-8f);
            ca.u[e]   = f2bf((q0 * kv[0] + q1 * kv[2]) * inv);
            ca.u[e+1] = f2bf((q0 * kv[1] + q1 * kv[3]) * inv);
            const float* kw = skv + (h + 16) * 6;
            float p0 = rs[e], p1 = rs[e+1];
            float iw = 1.f / (p0 * kw[4] + p1 * kw[5] + 1e-8f);
            cb.u[e]   = f2bf((p0 * kw[0] + p1 * kw[2]) * iw);
            cb.u[e+1] = f2bf((p0 * kw[1] + p1 * kw[3]) * iw);
        }
    }

    f32x4 acc[16];
    #pragma unroll
    for (int j = 0; j < 16; ++j) acc[j] = (f32x4){0.f, 0.f, 0.f, 0.f};
    #pragma unroll
    for (int j = 0; j < 16; ++j) {
        int Fg = (n0 >> 4) + cq + 4 * j;
        s16x8 b0 = *(const s16x8*)(W2 + ((size_t)(Fg * 2 + 0) * 64 + lane) * 8);
        s16x8 b1 = *(const s16x8*)(W2 + ((size_t)(Fg * 2 + 1) * 64 + lane) * 8);
        mfma16(acc[j], ca.v, b0);
        mfma16(acc[j], cb.v, b1);
    }

    const int wrow = rg * 16 + 4 * (lane >> 4);
    #pragma unroll
    for (int n = 0; n < 4; ++n) {
        #pragma unroll
        for (int i = 0; i < 4; ++i) {
            int col = cq * 16 + i * 64 + (lane & 15);
            #pragma unroll
            for (int r = 0; r < 4; ++r)
                cep[(wrow + r) * CEP_STRIDE + col] = acc[4 * n + i][r];
        }
        __syncthreads();
        #pragma unroll
        for (int p = 0; p < 4; ++p) {
            int row = p * 8 + (tid >> 6);
            int c4 = tid & 63;
            float4 c = *(const float4*)(cep + row * CEP_STRIDE + c4 * 4);
            int gcol = n0 + n * 256 + c4 * 4;
            size_t off = (size_t)(m0 + row) * DD + gcol;
            float4 xr = *(const float4*)(x + off);
            float4 ob = *(const float4*)(out_b + gcol);
            float4 o;
            o.x = c.x + ob.x + xr.x; o.y = c.y + ob.y + xr.y;
            o.z = c.z + ob.z + xr.z; o.w = c.w + ob.w + xr.w;
            *(float4*)(out + off) = o;
        }
        __syncthreads();
    }
}

extern "C" void kernel_launch(void* const* d_in, const int* in_sizes, int n_in,
                              void* d_out, int out_size, void* d_ws, size_t ws_size,
                              hipStream_t stream) {
    const float* x     = (const float*)d_in[0];
    const float* nw    = (const float*)d_in[1];
    const float* nb    = (const float*)d_in[2];
    const float* qkv_w = (const float*)d_in[3];
    const float* qkv_b = (const float*)d_in[4];
    const float* fm_w  = (const float*)d_in[5];
    const float* fm_b  = (const float*)d_in[6];
    const float* out_w = (const float*)d_in[7];
    const float* out_b = (const float*)d_in[8];
    float* out = (float*)d_out;

    char* ws = (char*)d_ws;
    ushort_t* W1 = (ushort_t*)ws;     ws += (size_t)NQKV * DD * 2;        // 786432 B
    ushort_t* W2 = (ushort_t*)ws;     ws += (size_t)DD * KKC * 2;         // 262144 B
    float* qfeat = (float*)ws;        ws += (size_t)NT * KKC * 4;         // 4 MiB
    float* kvpart = (float*)ws;       ws += (size_t)256 * 192 * 4;        // 196608 B
    float* kvstate = (float*)ws;      ws += (size_t)BB * HH * 6 * 4;      // 3072 B
    float* Svec = (float*)ws;         ws += (size_t)NQKV * 4;             // 768 B
    float* qb2 = (float*)ws;          ws += (size_t)NQKV * 4;             // 768 B

    k_pre<<<304, 256, 0, stream>>>(qkv_w, nw, nb, qkv_b, out_w, W1, W2, Svec, qb2);
    k_qkv<<<NT / QB, 512, 0, stream>>>(x, W1, Svec, qb2, fm_w, fm_b, qfeat, kvpart);
    k_red<<<3, 256, 0, stream>>>(kvpart, kvstate);
    k_out<<<(NT / 32) * 2, 512, 0, stream>>>(qfeat, kvstate, W2, out_b, x, out);
}

// Round 18
// 116.891 us; speedup vs baseline: 1.0403x; 1.0204x over previous
//
#include <hip/hip_runtime.h>
#include <hip/hip_bf16.h>
#include <stdint.h>

typedef unsigned short ushort_t;

#define BB 4
#define SS 4096
#define DD 2048
#define KKC 64      // K channels
#define HH 32
#define NT (BB*SS)  // 16384 tokens
#define NQKV 192
#define QB 64       // tokens per k_qkv block
#define BK 128      // K per step -> 16 steps

typedef float f32x4 __attribute__((ext_vector_type(4)));
typedef short s16x8 __attribute__((ext_vector_type(8)));

__device__ __forceinline__ ushort_t f2bf(float f) {
    union { float f; uint32_t u; } c; c.f = f;
    uint32_t u = c.u + 0x7fffu + ((c.u >> 16) & 1u);
    return (ushort_t)(u >> 16);
}
__device__ __forceinline__ float bf2f(ushort_t b) {
    union { uint32_t u; float f; } c; c.u = (uint32_t)b << 16; return c.f;
}

__device__ __forceinline__ uint32_t cvtpk(float lo, float hi) {
    uint32_t r;
    asm("v_cvt_pk_bf16_f32 %0, %1, %2" : "=v"(r) : "v"(lo), "v"(hi));
    return r;
}

// D = A(16x32) * B(32x16) + D, bf16 inputs, f32 acc.
// A lane map: row = l&15, k = 8*(l>>4)+e. B: col = l&15, k = 8*(l>>4)+e.
// C/D: col = l&15, row = 4*(l>>4)+reg.
__device__ __forceinline__ void mfma16(f32x4& d, s16x8 a, s16x8 b) {
    asm volatile("v_mfma_f32_16x16x32_bf16 %0, %1, %2, %0" : "+v"(d) : "v"(a), "v"(b));
}

// async global->LDS, 16B per lane; lds dest wave-uniform base (HW adds lane*16).
__device__ __forceinline__ void gload_lds16(const void* gsrc, void* ldst) {
    __builtin_amdgcn_global_load_lds(
        (const __attribute__((address_space(1))) unsigned int*)gsrc,
        (__attribute__((address_space(3))) unsigned int*)ldst,
        16, 0, 0);
}

// -------- merged weight pre-convert + per-col sums --------------------------
__global__ __launch_bounds__(256) void k_pre(
    const float* __restrict__ qkv_w, const float* __restrict__ nw,
    const float* __restrict__ nb, const float* __restrict__ qkv_b,
    const float* __restrict__ out_w,
    ushort_t* __restrict__ W1, ushort_t* __restrict__ W2,
    float* __restrict__ S, float* __restrict__ qb2) {
    int bid = blockIdx.x;
    if (bid < 256) {
        int E = bid * 256 + threadIdx.x;
        if (E < 49152) {
            int lane = E & 63; int rest = E >> 6;
            int f = rest % 12, g = rest / 12;
            int col = f * 16 + (lane & 15);
            int k0 = g * 32 + 8 * (lane >> 4);
            const float* src = qkv_w + (size_t)col * DD + k0;
            const float* wp = nw + k0;
            union { ushort_t u[8]; uint4 v; } cv;
            #pragma unroll
            for (int e = 0; e < 8; ++e) cv.u[e] = f2bf(src[e] * wp[e]);
            *(uint4*)(W1 + (size_t)E * 8) = cv.v;
        } else {
            int E2 = E - 49152;   // 16384 entries
            int lane = E2 & 63; int rest = E2 >> 6;
            int kk = rest & 1, F = rest >> 1;
            int n = F * 16 + (lane & 15);
            int k0 = kk * 32 + 8 * (lane >> 4);
            const float* src = out_w + (size_t)n * KKC + k0;
            union { ushort_t u[8]; uint4 v; } cv;
            #pragma unroll
            for (int e = 0; e < 8; ++e) cv.u[e] = f2bf(src[e]);
            *(uint4*)(W2 + (size_t)E2 * 8) = cv.v;
        }
    } else {
        int col = (bid - 256) * 4 + (threadIdx.x >> 6);   // 48 blocks -> 192 cols
        int lane = threadIdx.x & 63;
        float s = 0.f, qb = 0.f;
        for (int j = 0; j < 32; ++j) {
            int k = j * 64 + lane;
            float w = qkv_w[(size_t)col * DD + k];
            s += bf2f(f2bf(w * nw[k]));
            qb += nb[k] * w;
        }
        #pragma unroll
        for (int off = 32; off >= 1; off >>= 1) {
            s += __shfl_xor(s, off);
            qb += __shfl_xor(qb, off);
        }
        if (lane == 0) { S[col] = s; qb2[col] = qb + qkv_b[col]; }
    }
}

// ------- fused (LN-folded) QKV GEMM + stats + feature map + kv partials -----
// (R16 structure, unchanged: QB=64, BK=128, 16 steps, static dbuf, counted
//  vmcnt, reg-staged bf16 x with exact f32 stats.)
__global__ __launch_bounds__(512, 2) void k_qkv(
    const float* __restrict__ x, const ushort_t* __restrict__ W1,
    const float* __restrict__ S, const float* __restrict__ qb2,
    const float* __restrict__ fm_w, const float* __restrict__ fm_b,
    float* __restrict__ qfeat,          // [NT][64]
    float* __restrict__ kvpart)         // [256 blocks][192]
{
    __shared__ __align__(16) union {
        struct {
            ushort_t B0[3072 * 8];      // 49152 B
            ushort_t X0[QB * BK];       // 16384 B (bf16 x tile)
            ushort_t B1[3072 * 8];      // 49152 B
            ushort_t X1[QB * BK];       // 16384 B
        } s;                             // 131072 B
        float cep[QB][NQKV];            // 49152 B overlay (post-loop)
    } sm;
    __shared__ float kvred[32][16][6];   // 12288 B
    __shared__ float stats[QB][2];       // 512 B

    const int tid = threadIdx.x;
    const int wave = tid >> 6, lane = tid & 63;
    const int rg = wave & 1, ch = wave >> 1;
    const int m0 = blockIdx.x * QB;
    const int l15 = lane & 15, q4 = lane >> 4;

    const int row0 = tid >> 4;          // 0..31
    const int sl0 = tid & 15;
    const int row1 = row0 + 32;
    const float* xs0 = x + (size_t)(m0 + row0) * DD + sl0 * 8;
    const float* xs1 = x + (size_t)(m0 + row1) * DD + sl0 * 8;
    const int wb0 = row0 * 256 + ((sl0 ^ (row0 & 7)) << 4);
    const int wb1 = row1 * 256 + ((sl0 ^ (row1 & 7)) << 4);

    f32x4 acc[2][3];
    #pragma unroll
    for (int rf = 0; rf < 2; ++rf)
        #pragma unroll
        for (int f = 0; f < 3; ++f) acc[rf][f] = (f32x4){0.f, 0.f, 0.f, 0.f};
    float st1[2] = {0.f, 0.f}, st2[2] = {0.f, 0.f};

    float4 xa[4];

#define XISSUE(T) do { \
        xa[0] = *(const float4*)(xs0 + (size_t)(T) * BK); \
        xa[1] = *(const float4*)(xs0 + (size_t)(T) * BK + 4); \
        xa[2] = *(const float4*)(xs1 + (size_t)(T) * BK); \
        xa[3] = *(const float4*)(xs1 + (size_t)(T) * BK + 4); \
    } while (0)

#define BSTAGE(T, BARR) do { \
        _Pragma("unroll") \
        for (int i_ = 0; i_ < 6; ++i_) { \
            int eb_ = i_ * 512 + wave * 64; \
            gload_lds16((const char*)W1 + ((size_t)(T) * 3072 + eb_ + lane) * 16, \
                        (char*)(BARR) + eb_ * 16); \
        } \
    } while (0)

#define CVTW(XARR) do { \
        st1[0] += xa[0].x+xa[0].y+xa[0].z+xa[0].w + xa[1].x+xa[1].y+xa[1].z+xa[1].w; \
        st2[0] += xa[0].x*xa[0].x+xa[0].y*xa[0].y+xa[0].z*xa[0].z+xa[0].w*xa[0].w \
                + xa[1].x*xa[1].x+xa[1].y*xa[1].y+xa[1].z*xa[1].z+xa[1].w*xa[1].w; \
        st1[1] += xa[2].x+xa[2].y+xa[2].z+xa[2].w + xa[3].x+xa[3].y+xa[3].z+xa[3].w; \
        st2[1] += xa[2].x*xa[2].x+xa[2].y*xa[2].y+xa[2].z*xa[2].z+xa[2].w*xa[2].w \
                + xa[3].x*xa[3].x+xa[3].y*xa[3].y+xa[3].z*xa[3].z+xa[3].w*xa[3].w; \
        uint4 w0_, w1_; \
        w0_.x = cvtpk(xa[0].x, xa[0].y); w0_.y = cvtpk(xa[0].z, xa[0].w); \
        w0_.z = cvtpk(xa[1].x, xa[1].y); w0_.w = cvtpk(xa[1].z, xa[1].w); \
        w1_.x = cvtpk(xa[2].x, xa[2].y); w1_.y = cvtpk(xa[2].z, xa[2].w); \
        w1_.z = cvtpk(xa[3].x, xa[3].y); w1_.w = cvtpk(xa[3].z, xa[3].w); \
        *(uint4*)((char*)(XARR) + wb0) = w0_; \
        *(uint4*)((char*)(XARR) + wb1) = w1_; \
    } while (0)

#define STEP_BODY(BARR, XARR) do { \
        const char* bp_ = (const char*)(BARR); \
        const char* xp_ = (const char*)(XARR); \
        const int r0_ = rg * 32 + l15, r1_ = r0_ + 16; \
        _Pragma("unroll") \
        for (int kb_ = 0; kb_ < 4; ++kb_) { \
            s16x8 a0_ = *(const s16x8*)(xp_ + r0_ * 256 + (((kb_ * 4 + q4) ^ (r0_ & 7)) << 4)); \
            s16x8 a1_ = *(const s16x8*)(xp_ + r1_ * 256 + (((kb_ * 4 + q4) ^ (r1_ & 7)) << 4)); \
            __builtin_amdgcn_s_setprio(1); \
            _Pragma("unroll") \
            for (int f_ = 0; f_ < 3; ++f_) { \
                s16x8 b_ = *(const s16x8*)(bp_ + ((kb_ * 12 + ch * 3 + f_) * 64 + lane) * 16); \
                mfma16(acc[0][f_], a0_, b_); \
                mfma16(acc[1][f_], a1_, b_); \
            } \
            __builtin_amdgcn_s_setprio(0); \
        } \
    } while (0)

#define WAITN(N) asm volatile("s_waitcnt vmcnt(" #N ")" ::: "memory")
#define LGKM0()  asm volatile("s_waitcnt lgkmcnt(0)" ::: "memory")
#define BARR_()  do { __builtin_amdgcn_s_barrier(); __builtin_amdgcn_sched_barrier(0); } while (0)

#define ITER(T, CB, CX, NB_, NX_) do { \
        XISSUE((T) + 1); \
        BSTAGE((T) + 1, NB_); \
        STEP_BODY(CB, CX); \
        WAITN(6); \
        CVTW(NX_); \
        LGKM0(); \
        WAITN(0); \
        BARR_(); \
    } while (0)

    XISSUE(0);
    BSTAGE(0, sm.s.B0);
    WAITN(6);
    CVTW(sm.s.X0);
    LGKM0();
    WAITN(0);
    BARR_();

    #pragma unroll
    for (int tp = 0; tp < 7; ++tp) {
        ITER(2 * tp,     sm.s.B0, sm.s.X0, sm.s.B1, sm.s.X1);
        ITER(2 * tp + 1, sm.s.B1, sm.s.X1, sm.s.B0, sm.s.X0);
    }
    ITER(14, sm.s.B0, sm.s.X0, sm.s.B1, sm.s.X1);
    STEP_BODY(sm.s.B1, sm.s.X1);        // step 15

    #pragma unroll
    for (int j = 0; j < 2; ++j) {
        st1[j] += __shfl_xor(st1[j], 1); st2[j] += __shfl_xor(st2[j], 1);
        st1[j] += __shfl_xor(st1[j], 2); st2[j] += __shfl_xor(st2[j], 2);
        st1[j] += __shfl_xor(st1[j], 4); st2[j] += __shfl_xor(st2[j], 4);
        st1[j] += __shfl_xor(st1[j], 8); st2[j] += __shfl_xor(st2[j], 8);
    }
    if (l15 == 0) {
        #pragma unroll
        for (int j = 0; j < 2; ++j) {
            int row = wave * 4 + q4 + j * 32;
            float mu = st1[j] * (1.f / DD);
            float var = st2[j] * (1.f / DD) - mu * mu;
            stats[row][0] = mu;
            stats[row][1] = rsqrtf(var + 1e-5f);
        }
    }

    #pragma unroll
    for (int rf = 0; rf < 2; ++rf) {
        int rbase = rg * 32 + rf * 16 + q4 * 4;
        #pragma unroll
        for (int f = 0; f < 3; ++f) {
            int col = (ch * 3 + f) * 16 + l15;
            #pragma unroll
            for (int r = 0; r < 4; ++r)
                sm.cep[rbase + r][col] = acc[rf][f][r];
        }
    }
    __syncthreads();

    const int h = tid & 31, gg = tid >> 5;     // gg 0..15, 4 tokens each
    const float fm00 = fm_w[0], fm01 = fm_w[1], fm10 = fm_w[2], fm11 = fm_w[3];
    const float fb0 = fm_b[0], fb1 = fm_b[1];
    const float Sq0 = S[2*h],      Sq1 = S[2*h+1],      cq0 = qb2[2*h],      cq1 = qb2[2*h+1];
    const float Sk0 = S[64+2*h],   Sk1 = S[64+2*h+1],   ck0 = qb2[64+2*h],   ck1 = qb2[64+2*h+1];
    const float Sv0 = S[128+2*h],  Sv1 = S[128+2*h+1],  cv0 = qb2[128+2*h],  cv1 = qb2[128+2*h+1];
    float kv00=0, kv01=0, kv10=0, kv11=0, ks0=0, ks1=0;
    #pragma unroll
    for (int i = 0; i < 4; ++i) {
        int tt = gg * 4 + i;
        float mu = stats[tt][0], rs = stats[tt][1];
        float f = mu * rs;
        float q0 = rs * sm.cep[tt][2*h]      - f * Sq0 + cq0;
        float q1 = rs * sm.cep[tt][2*h+1]    - f * Sq1 + cq1;
        float k0 = rs * sm.cep[tt][64+2*h]   - f * Sk0 + ck0;
        float k1 = rs * sm.cep[tt][64+2*h+1] - f * Sk1 + ck1;
        float v0 = rs * sm.cep[tt][128+2*h]  - f * Sv0 + cv0;
        float v1 = rs * sm.cep[tt][128+2*h+1]- f * Sv1 + cv1;
        float qp0 = fmaxf(fm00*q0 + fm01*q1 + fb0, 0.f);
        float qp1 = fmaxf(fm10*q0 + fm11*q1 + fb1, 0.f);
        float kp0 = fmaxf(fm00*k0 + fm01*k1 + fb0, 0.f);
        float kp1 = fmaxf(fm10*k0 + fm11*k1 + fb1, 0.f);
        *(float2*)(qfeat + (size_t)(m0 + tt) * KKC + 2*h) = make_float2(qp0, qp1);
        kv00 += kp0*v0; kv01 += kp0*v1; kv10 += kp1*v0; kv11 += kp1*v1;
        ks0 += kp0; ks1 += kp1;
    }
    kvred[h][gg][0]=kv00; kvred[h][gg][1]=kv01; kvred[h][gg][2]=kv10;
    kvred[h][gg][3]=kv11; kvred[h][gg][4]=ks0;  kvred[h][gg][5]=ks1;
    __syncthreads();
    if (tid < 192) {
        int h2 = tid / 6, j = tid % 6;
        float s = 0.f;
        #pragma unroll
        for (int g2 = 0; g2 < 16; ++g2) s += kvred[h2][g2][j];
        kvpart[(size_t)blockIdx.x * 192 + tid] = s;
    }
#undef XISSUE
#undef BSTAGE
#undef CVTW
#undef STEP_BODY
#undef WAITN
#undef LGKM0
#undef BARR_
#undef ITER
}

// ---------------- reduce kv partials (deterministic) ----------------
__global__ void k_red(const float* __restrict__ kvpart, float* __restrict__ kvstate) {
    int idx = blockIdx.x * 256 + threadIdx.x;   // 768 = B*H*6
    if (idx >= BB * HH * 6) return;
    int b = idx / 192, r = idx % 192;
    float s = 0.f;
    for (int blk = 0; blk < 64; ++blk)
        s += kvpart[(size_t)(b * 64 + blk) * 192 + r];
    kvstate[idx] = s;  // [b][h][6]
}

// ---------------- out-projection GEMM (attn inline) + residual -------------
// NT stores for `out` (never re-read): avoid L3 allocation so the x lines
// warmed by k_qkv stay resident for this kernel's residual reads.
// (f32x4 clang ext-vector for __builtin_nontemporal_store — HIP float4 is
//  a struct and rejected by the builtin.)
#define CEP_STRIDE 260
__global__ __launch_bounds__(512, 4) void k_out(
    const float* __restrict__ qfeat, const float* __restrict__ kvstate,
    const ushort_t* __restrict__ W2, const float* __restrict__ out_b,
    const float* __restrict__ x, float* __restrict__ out) {
    __shared__ float skv[192];
    __shared__ __align__(16) float cep[32 * CEP_STRIDE];   // 33280 B
    const int tid = threadIdx.x, wave = tid >> 6, lane = tid & 63;
    const int rg = wave & 1, cq = wave >> 1;
    const int mb = blockIdx.x >> 1, nb = blockIdx.x & 1;
    const int m0 = mb * 32;
    const int n0 = nb * 1024;
    const int b = m0 >> 12;
    if (tid < 192) skv[tid] = kvstate[b * 192 + tid];

    const int arow = m0 + rg * 16 + (lane & 15);
    const int ksub = 8 * (lane >> 4);
    float4 qa0 = *(const float4*)(qfeat + (size_t)arow * KKC + ksub);
    float4 qa1 = *(const float4*)(qfeat + (size_t)arow * KKC + ksub + 4);
    float4 qb0 = *(const float4*)(qfeat + (size_t)arow * KKC + 32 + ksub);
    float4 qb1 = *(const float4*)(qfeat + (size_t)arow * KKC + 32 + ksub + 4);
    __syncthreads();

    union { ushort_t u[8]; s16x8 v; } ca, cb;
    {
        float qs[8] = {qa0.x,qa0.y,qa0.z,qa0.w,qa1.x,qa1.y,qa1.z,qa1.w};
        float rs[8] = {qb0.x,qb0.y,qb0.z,qb0.w,qb1.x,qb1.y,qb1.z,qb1.w};
        #pragma unroll
        for (int e = 0; e < 8; e += 2) {
            int h = (ksub + e) >> 1;
            const float* kv = skv + h * 6;
            float q0 = qs[e], q1 = qs[e+1];
            float inv = 1.f / (q0 * kv[4] + q1 * kv[5] + 1e-8f);
            ca.u[e]   = f2bf((q0 * kv[0] + q1 * kv[2]) * inv);
            ca.u[e+1] = f2bf((q0 * kv[1] + q1 * kv[3]) * inv);
            const float* kw = skv + (h + 16) * 6;
            float p0 = rs[e], p1 = rs[e+1];
            float iw = 1.f / (p0 * kw[4] + p1 * kw[5] + 1e-8f);
            cb.u[e]   = f2bf((p0 * kw[0] + p1 * kw[2]) * iw);
            cb.u[e+1] = f2bf((p0 * kw[1] + p1 * kw[3]) * iw);
        }
    }

    f32x4 acc[16];
    #pragma unroll
    for (int j = 0; j < 16; ++j) acc[j] = (f32x4){0.f, 0.f, 0.f, 0.f};
    #pragma unroll
    for (int j = 0; j < 16; ++j) {
        int Fg = (n0 >> 4) + cq + 4 * j;
        s16x8 b0 = *(const s16x8*)(W2 + ((size_t)(Fg * 2 + 0) * 64 + lane) * 8);
        s16x8 b1 = *(const s16x8*)(W2 + ((size_t)(Fg * 2 + 1) * 64 + lane) * 8);
        mfma16(acc[j], ca.v, b0);
        mfma16(acc[j], cb.v, b1);
    }

    const int wrow = rg * 16 + 4 * (lane >> 4);
    #pragma unroll
    for (int n = 0; n < 4; ++n) {
        #pragma unroll
        for (int i = 0; i < 4; ++i) {
            int col = cq * 16 + i * 64 + (lane & 15);
            #pragma unroll
            for (int r = 0; r < 4; ++r)
                cep[(wrow + r) * CEP_STRIDE + col] = acc[4 * n + i][r];
        }
        __syncthreads();
        #pragma unroll
        for (int p = 0; p < 4; ++p) {
            int row = p * 8 + (tid >> 6);
            int c4 = tid & 63;
            float4 c = *(const float4*)(cep + row * CEP_STRIDE + c4 * 4);
            int gcol = n0 + n * 256 + c4 * 4;
            size_t off = (size_t)(m0 + row) * DD + gcol;
            float4 xr = *(const float4*)(x + off);
            float4 ob = *(const float4*)(out_b + gcol);
            f32x4 o;
            o[0] = c.x + ob.x + xr.x; o[1] = c.y + ob.y + xr.y;
            o[2] = c.z + ob.z + xr.z; o[3] = c.w + ob.w + xr.w;
            __builtin_nontemporal_store(o, (f32x4*)(out + off));
        }
        __syncthreads();
    }
}

extern "C" void kernel_launch(void* const* d_in, const int* in_sizes, int n_in,
                              void* d_out, int out_size, void* d_ws, size_t ws_size,
                              hipStream_t stream) {
    const float* x     = (const float*)d_in[0];
    const float* nw    = (const float*)d_in[1];
    const float* nb    = (const float*)d_in[2];
    const float* qkv_w = (const float*)d_in[3];
    const float* qkv_b = (const float*)d_in[4];
    const float* fm_w  = (const float*)d_in[5];
    const float* fm_b  = (const float*)d_in[6];
    const float* out_w = (const float*)d_in[7];
    const float* out_b = (const float*)d_in[8];
    float* out = (float*)d_out;

    char* ws = (char*)d_ws;
    ushort_t* W1 = (ushort_t*)ws;     ws += (size_t)NQKV * DD * 2;        // 786432 B
    ushort_t* W2 = (ushort_t*)ws;     ws += (size_t)DD * KKC * 2;         // 262144 B
    float* qfeat = (float*)ws;        ws += (size_t)NT * KKC * 4;         // 4 MiB
    float* kvpart = (float*)ws;       ws += (size_t)256 * 192 * 4;        // 196608 B
    float* kvstate = (float*)ws;      ws += (size_t)BB * HH * 6 * 4;      // 3072 B
    float* Svec = (float*)ws;         ws += (size_t)NQKV * 4;             // 768 B
    float* qb2 = (float*)ws;          ws += (size_t)NQKV * 4;             // 768 B

    k_pre<<<304, 256, 0, stream>>>(qkv_w, nw, nb, qkv_b, out_w, W1, W2, Svec, qb2);
    k_qkv<<<NT / QB, 512, 0, stream>>>(x, W1, Svec, qb2, fm_w, fm_b, qfeat, kvpart);
    k_red<<<3, 256, 0, stream>>>(kvpart, kvstate);
    k_out<<<(NT / 32) * 2, 512, 0, stream>>>(qfeat, kvstate, W2, out_b, x, out);
}